// Round 1
// baseline (1935.797 us; speedup 1.0000x reference)
//
#include <hip/hip_runtime.h>

namespace {

constexpr int FEAT   = 128;
constexpr int NRBF   = 20;
constexpr int EPB    = 16;       // edges per block
constexpr int NNODES = 25000;
constexpr int NEDGES = 400000;
constexpr float PI_F = 3.14159265358979323846f;

__global__ __launch_bounds__(256) void msg_kernel(
    const float* __restrict__ s_j, const float* __restrict__ v_j,
    const float* __restrict__ r_ij, const int* __restrict__ nbrs,
    const float* __restrict__ W1, const float* __restrict__ b1,
    const float* __restrict__ W2, const float* __restrict__ b2,
    const float* __restrict__ Wd, const float* __restrict__ bd,
    float* __restrict__ ds_out, float* __restrict__ dv_out)
{
    __shared__ float s_s[EPB][FEAT];        // gathered s_j rows
    __shared__ float s_h[EPB][FEAT];        // swish(s@W1+b1)
    __shared__ float s_inv[EPB][3*FEAT];    // phi * w_s
    __shared__ float s_rbf[EPB][NRBF];
    __shared__ float s_unit[EPB][3];
    __shared__ int   s_src[EPB];
    __shared__ int   s_dst[EPB];

    const int tid = threadIdx.x;
    const int e0  = blockIdx.x * EPB;

    // ---- Phase 0: edge metadata (dist, unit, rbf) ----
    if (tid < EPB) {
        const int e = e0 + tid;
        s_dst[tid] = nbrs[2*e + 0];
        s_src[tid] = nbrs[2*e + 1];
        const float r0 = r_ij[3*e + 0];
        const float r1 = r_ij[3*e + 1];
        const float r2 = r_ij[3*e + 2];
        // reference: sqrt(sum(r*r + EPS)) == sqrt(dot + 3*EPS)
        const float d     = sqrtf(r0*r0 + r1*r1 + r2*r2 + 3e-15f);
        const float inv_d = 1.0f / d;
        s_unit[tid][0] = r0 * inv_d;
        s_unit[tid][1] = r1 * inv_d;
        s_unit[tid][2] = r2 * inv_d;
        #pragma unroll
        for (int n = 0; n < NRBF; ++n)
            s_rbf[tid][n] = __sinf((float)(n+1) * (PI_F / 5.0f) * d) * inv_d;
    }
    __syncthreads();

    // ---- Phase 1: gather s_j rows into LDS (float4, coalesced per row) ----
    #pragma unroll
    for (int p = 0; p < (EPB*FEAT/4)/256; ++p) {   // 2 iterations
        const int v = tid + p*256;
        const int e = v >> 5;      // 32 float4 per 128-float row
        const int c = v & 31;
        const float4 val = reinterpret_cast<const float4*>(s_j + (size_t)s_src[e]*FEAT)[c];
        reinterpret_cast<float4*>(&s_s[e][0])[c] = val;
    }
    __syncthreads();

    const int j    = tid & (FEAT - 1);   // output column 0..127
    const int half = tid >> 7;           // 0/1 -> edges [0..7] / [8..15]

    // ---- Phase 2: h = swish(s @ W1 + b1) ----
    {
        float acc[8];
        #pragma unroll
        for (int i = 0; i < 8; ++i) acc[i] = 0.f;

        for (int k = 0; k < FEAT; k += 4) {
            float w[4];
            #pragma unroll
            for (int kk = 0; kk < 4; ++kk) w[kk] = W1[(k+kk)*FEAT + j];
            #pragma unroll
            for (int i = 0; i < 8; ++i) {
                const float4 sv = *reinterpret_cast<const float4*>(&s_s[half*8 + i][k]);
                acc[i] += sv.x*w[0] + sv.y*w[1] + sv.z*w[2] + sv.w*w[3];
            }
        }
        const float b1j = b1[j];
        #pragma unroll
        for (int i = 0; i < 8; ++i) {
            const float x   = acc[i] + b1j;
            const float sig = 1.0f / (1.0f + __expf(-x));
            s_h[half*8 + i][j] = x * sig;
        }
    }
    __syncthreads();

    // ---- Phase 3: phi = h @ W2 + b2 ; inv = phi * (rbf @ Wd + bd) ----
    {
        float acc2[3][8];
        #pragma unroll
        for (int mc = 0; mc < 3; ++mc)
            #pragma unroll
            for (int i = 0; i < 8; ++i) acc2[mc][i] = 0.f;

        for (int k = 0; k < FEAT; k += 4) {
            float w0[4], w1[4], w2[4];
            #pragma unroll
            for (int kk = 0; kk < 4; ++kk) {
                const int row = (k+kk)*3*FEAT;
                w0[kk] = W2[row + j];
                w1[kk] = W2[row + FEAT   + j];
                w2[kk] = W2[row + 2*FEAT + j];
            }
            #pragma unroll
            for (int i = 0; i < 8; ++i) {
                const float4 hv = *reinterpret_cast<const float4*>(&s_h[half*8 + i][k]);
                acc2[0][i] += hv.x*w0[0] + hv.y*w0[1] + hv.z*w0[2] + hv.w*w0[3];
                acc2[1][i] += hv.x*w1[0] + hv.y*w1[1] + hv.z*w1[2] + hv.w*w1[3];
                acc2[2][i] += hv.x*w2[0] + hv.y*w2[1] + hv.z*w2[2] + hv.w*w2[3];
            }
        }

        #pragma unroll
        for (int mc = 0; mc < 3; ++mc) {
            const int m = mc*FEAT + j;
            float wd[NRBF];
            #pragma unroll
            for (int n = 0; n < NRBF; ++n) wd[n] = Wd[n*3*FEAT + m];
            const float b2m = b2[m];
            const float bdm = bd[m];
            #pragma unroll
            for (int i = 0; i < 8; ++i) {
                const int e = half*8 + i;
                float ws = bdm;
                #pragma unroll
                for (int n = 0; n < NRBF; ++n) ws += s_rbf[e][n] * wd[n];
                const float phi = acc2[mc][i] + b2m;
                s_inv[e][m] = phi * ws;
            }
        }
    }
    __syncthreads();

    // ---- Phase 4: scatter-add into outputs ----
    #pragma unroll
    for (int p = 0; p < (EPB*FEAT)/256; ++p) {     // 8 iterations
        const int pair = tid + p*256;
        const int e = pair >> 7;
        const int f = pair & (FEAT - 1);
        const float i0 = s_inv[e][3*f + 0];
        const float i1 = s_inv[e][3*f + 1];
        const float i2 = s_inv[e][3*f + 2];
        const int src = s_src[e];
        const int dst = s_dst[e];
        const float* vj = v_j + (size_t)src*(3*FEAT) + 3*f;
        atomicAdd(ds_out + (size_t)dst*FEAT + f, i1);
        float* dvp = dv_out + (size_t)dst*(3*FEAT) + 3*f;
        atomicAdd(dvp + 0, i2*s_unit[e][0] + i0*vj[0]);
        atomicAdd(dvp + 1, i2*s_unit[e][1] + i0*vj[1]);
        atomicAdd(dvp + 2, i2*s_unit[e][2] + i0*vj[2]);
    }
}

} // anonymous namespace

extern "C" void kernel_launch(void* const* d_in, const int* in_sizes, int n_in,
                              void* d_out, int out_size, void* d_ws, size_t ws_size,
                              hipStream_t stream)
{
    const float* s_j  = (const float*)d_in[0];
    const float* v_j  = (const float*)d_in[1];
    const float* r_ij = (const float*)d_in[2];
    const int*   nbrs = (const int*)d_in[3];
    const float* W1   = (const float*)d_in[4];
    const float* b1   = (const float*)d_in[5];
    const float* W2   = (const float*)d_in[6];
    const float* b2   = (const float*)d_in[7];
    const float* Wd   = (const float*)d_in[8];
    const float* bd   = (const float*)d_in[9];

    float* ds_out = (float*)d_out;
    float* dv_out = ds_out + (size_t)NNODES * FEAT;

    // outputs are re-poisoned to 0xAA before every timed launch
    hipMemsetAsync(d_out, 0, (size_t)out_size * sizeof(float), stream);

    msg_kernel<<<NEDGES / EPB, 256, 0, stream>>>(
        s_j, v_j, r_ij, nbrs, W1, b1, W2, b2, Wd, bd, ds_out, dv_out);
}

// Round 2
// 1757.215 us; speedup vs baseline: 1.1016x; 1.1016x over previous
//
#include <hip/hip_runtime.h>

namespace {

constexpr int FEAT   = 128;
constexpr int NRBF   = 20;
constexpr int EPB    = 32;        // edges per block
constexpr int NNODES = 25000;
constexpr int NEDGES = 400000;
constexpr int NBLK   = NEDGES / EPB;   // 12500
constexpr float PI_F = 3.14159265358979323846f;

using f32x4 = __attribute__((ext_vector_type(4))) float;
using s16x8 = __attribute__((ext_vector_type(8))) short;
using s16x4 = __attribute__((ext_vector_type(4))) short;

// packed-weight layout in d_ws (bf16 elements)
constexpr int PW1_ELEMS = 8  * 4 * 64 * 8;   // 16384  (8 ntiles, 4 ksteps)
constexpr int PW2_ELEMS = 24 * 4 * 64 * 8;   // 49152
constexpr int PWD_ELEMS = 24 * 1 * 64 * 8;   // 12288  (1 kstep, K=32 zero-padded)
constexpr int PW1_OFF = 0;
constexpr int PW2_OFF = PW1_ELEMS;
constexpr int PWD_OFF = PW1_ELEMS + PW2_ELEMS;
constexpr int PT_TOTAL = PW1_ELEMS + PW2_ELEMS + PWD_ELEMS;  // 77824

__device__ inline unsigned short f2bf(float f) {
    unsigned u = __builtin_bit_cast(unsigned, f);
    u += 0x7fffu + ((u >> 16) & 1u);          // round-to-nearest-even
    return (unsigned short)(u >> 16);
}
__device__ inline float bf2f(unsigned short h) {
    unsigned u = ((unsigned)h) << 16;
    return __builtin_bit_cast(float, u);
}

// ---- prep: pack W1/W2/Wd into per-lane MFMA B-fragment order (bf16) ----
// B-frag layout for mfma_f32_16x16x32_bf16: element (k,n): n = nt*16 + (lane&15),
// k = ks*32 + (lane>>4)*8 + r, r = 0..7 contiguous in the 16B chunk.
__global__ __launch_bounds__(256) void prep_kernel(
    const float* __restrict__ W1, const float* __restrict__ W2,
    const float* __restrict__ Wd, short* __restrict__ pw)
{
    const int idx = blockIdx.x * 256 + threadIdx.x;
    if (idx >= PT_TOTAL) return;
    float val;
    if (idx < PW2_OFF) {
        const int t = idx;
        const int r = t & 7, lane = (t >> 3) & 63, ks = (t >> 9) & 3, nt = t >> 11;
        const int k = ks*32 + (lane>>4)*8 + r, n = nt*16 + (lane & 15);
        val = W1[k*128 + n];
    } else if (idx < PWD_OFF) {
        const int t = idx - PW2_OFF;
        const int r = t & 7, lane = (t >> 3) & 63, ks = (t >> 9) & 3, nt = t >> 11;
        const int k = ks*32 + (lane>>4)*8 + r, n = nt*16 + (lane & 15);
        val = W2[k*384 + n];
    } else {
        const int t = idx - PWD_OFF;
        const int r = t & 7, lane = (t >> 3) & 63, nt = t >> 9;
        const int k = (lane>>4)*8 + r, n = nt*16 + (lane & 15);
        val = (k < NRBF) ? Wd[k*384 + n] : 0.f;
    }
    pw[idx] = (short)f2bf(val);
}

// ---- main fused kernel ----
__global__ __launch_bounds__(256) void msg_kernel(
    const float* __restrict__ s_j, const float* __restrict__ v_j,
    const float* __restrict__ r_ij, const int* __restrict__ nbrs,
    const float* __restrict__ b1, const float* __restrict__ b2,
    const float* __restrict__ bd, const short* __restrict__ pw,
    float* __restrict__ ds_out, float* __restrict__ dv_out)
{
    // XOR-swizzled bf16 tiles: element (m,k) stored at [m*LD + (k ^ ((m&7)<<3))]
    __shared__ short sA[EPB * 128];      // gathered s rows        (8 KB)
    __shared__ short sH[EPB * 128];      // swish(s@W1+b1)         (8 KB)
    __shared__ short sR[EPB * 64];       // rbf, K=32 zero-padded  (4 KB)
    __shared__ short sI[EPB * 384];      // inv = phi*w_s (unswizzled, 24 KB)
    __shared__ float sU[EPB][3];
    __shared__ int   sSrc[EPB], sDst[EPB];

    const int tid = threadIdx.x;
    const int w   = tid >> 6;          // wave 0..3
    const int l   = tid & 63;          // lane
    const int mr  = l & 15;            // C col / A row selector
    const int g   = l >> 4;            // lane group 0..3
    const int e0  = blockIdx.x * EPB;

    // ---- P0a: per-edge meta (threads 0..31) ----
    if (tid < EPB) {
        const int e = e0 + tid;
        sDst[tid] = nbrs[2*e + 0];
        sSrc[tid] = nbrs[2*e + 1];
        const float r0 = r_ij[3*e+0], r1 = r_ij[3*e+1], r2 = r_ij[3*e+2];
        const float d     = sqrtf(r0*r0 + r1*r1 + r2*r2 + 3e-15f);
        const float inv_d = 1.0f / d;
        sU[tid][0] = r0*inv_d; sU[tid][1] = r1*inv_d; sU[tid][2] = r2*inv_d;
        const int xr = (tid & 7) << 3;
        #pragma unroll
        for (int k = 0; k < 64; ++k) {
            const float v = (k < NRBF) ? __sinf((float)(k+1)*(PI_F/5.0f)*d)*inv_d : 0.f;
            sR[tid*64 + (k ^ xr)] = (short)f2bf(v);
        }
    }

    // ---- P0b: gather s_j rows -> bf16 LDS (all threads) ----
    #pragma unroll
    for (int p = 0; p < 4; ++p) {
        const int v  = tid + p*256;          // 0..1023 float4 slots
        const int e  = v >> 5;
        const int c4 = (v & 31) * 4;         // first f32 col of this chunk
        const int src = nbrs[2*(e0 + e) + 1];
        const float4 f = reinterpret_cast<const float4*>(s_j + (size_t)src*FEAT)[v & 31];
        s16x4 h;
        h.x = (short)f2bf(f.x); h.y = (short)f2bf(f.y);
        h.z = (short)f2bf(f.z); h.w = (short)f2bf(f.w);
        *reinterpret_cast<s16x4*>(&sA[e*128 + (c4 ^ ((e & 7) << 3))]) = h;
    }
    __syncthreads();

    // ---- P1: GEMM1  h = swish(s@W1 + b1) ----
    {
        s16x8 aS[2][4];
        #pragma unroll
        for (int mt = 0; mt < 2; ++mt) {
            const int m = mt*16 + mr;
            const int xr = (m & 7) << 3;
            #pragma unroll
            for (int ks = 0; ks < 4; ++ks)
                aS[mt][ks] = *reinterpret_cast<const s16x8*>(&sA[m*128 + ((ks*32 + g*8) ^ xr)]);
        }
        const s16x8* pW1 = reinterpret_cast<const s16x8*>(pw + PW1_OFF);
        #pragma unroll
        for (int i = 0; i < 2; ++i) {
            const int nt = w*2 + i;
            const int n  = nt*16 + mr;
            const float b1n = b1[n];
            f32x4 acc[2] = {f32x4{0,0,0,0}, f32x4{0,0,0,0}};
            #pragma unroll
            for (int ks = 0; ks < 4; ++ks) {
                const s16x8 b = pW1[(nt*4 + ks)*64 + l];
                acc[0] = __builtin_amdgcn_mfma_f32_16x16x32_bf16(aS[0][ks], b, acc[0], 0, 0, 0);
                acc[1] = __builtin_amdgcn_mfma_f32_16x16x32_bf16(aS[1][ks], b, acc[1], 0, 0, 0);
            }
            #pragma unroll
            for (int mt = 0; mt < 2; ++mt)
                #pragma unroll
                for (int r = 0; r < 4; ++r) {
                    const int m = mt*16 + g*4 + r;
                    const float x = acc[mt][r] + b1n;
                    const float hsw = x / (1.0f + __expf(-x));
                    sH[m*128 + (n ^ ((m & 7) << 3))] = (short)f2bf(hsw);
                }
        }
    }
    __syncthreads();

    // ---- P2: GEMM2 phi = h@W2+b2 ; ws = rbf@Wd+bd (MFMA, K=32 padded); inv ----
    {
        s16x8 aH[2][4], aR[2];
        #pragma unroll
        for (int mt = 0; mt < 2; ++mt) {
            const int m = mt*16 + mr;
            const int xr = (m & 7) << 3;
            #pragma unroll
            for (int ks = 0; ks < 4; ++ks)
                aH[mt][ks] = *reinterpret_cast<const s16x8*>(&sH[m*128 + ((ks*32 + g*8) ^ xr)]);
            aR[mt] = *reinterpret_cast<const s16x8*>(&sR[m*64 + ((g*8) ^ xr)]);
        }
        const s16x8* pW2 = reinterpret_cast<const s16x8*>(pw + PW2_OFF);
        const s16x8* pWd = reinterpret_cast<const s16x8*>(pw + PWD_OFF);
        #pragma unroll
        for (int i = 0; i < 6; ++i) {
            const int nt = w*6 + i;
            const int n  = nt*16 + mr;            // 0..383
            const float b2n = b2[n], bdn = bd[n];
            f32x4 acc[2]  = {f32x4{0,0,0,0}, f32x4{0,0,0,0}};
            f32x4 accw[2] = {f32x4{0,0,0,0}, f32x4{0,0,0,0}};
            #pragma unroll
            for (int ks = 0; ks < 4; ++ks) {
                const s16x8 b = pW2[(nt*4 + ks)*64 + l];
                acc[0] = __builtin_amdgcn_mfma_f32_16x16x32_bf16(aH[0][ks], b, acc[0], 0, 0, 0);
                acc[1] = __builtin_amdgcn_mfma_f32_16x16x32_bf16(aH[1][ks], b, acc[1], 0, 0, 0);
            }
            const s16x8 bw = pWd[nt*64 + l];
            accw[0] = __builtin_amdgcn_mfma_f32_16x16x32_bf16(aR[0], bw, accw[0], 0, 0, 0);
            accw[1] = __builtin_amdgcn_mfma_f32_16x16x32_bf16(aR[1], bw, accw[1], 0, 0, 0);
            #pragma unroll
            for (int mt = 0; mt < 2; ++mt)
                #pragma unroll
                for (int r = 0; r < 4; ++r) {
                    const int m = mt*16 + g*4 + r;
                    const float inv = (acc[mt][r] + b2n) * (accw[mt][r] + bdn);
                    sI[m*384 + n] = (short)f2bf(inv);
                }
        }
    }
    __syncthreads();

    // ---- P3: scatter-add ----
    #pragma unroll
    for (int p = 0; p < (EPB*FEAT)/256; ++p) {        // 16 iterations
        const int pair = tid + p*256;
        const int e = pair >> 7;
        const int f = pair & (FEAT - 1);
        const float i0 = bf2f((unsigned short)sI[e*384 + 3*f + 0]);
        const float i1 = bf2f((unsigned short)sI[e*384 + 3*f + 1]);
        const float i2 = bf2f((unsigned short)sI[e*384 + 3*f + 2]);
        const int src = sSrc[e];
        const int dst = sDst[e];
        const float* vj = v_j + (size_t)src*(3*FEAT) + 3*f;
        atomicAdd(ds_out + (size_t)dst*FEAT + f, i1);
        float* dvp = dv_out + (size_t)dst*(3*FEAT) + 3*f;
        atomicAdd(dvp + 0, i2*sU[e][0] + i0*vj[0]);
        atomicAdd(dvp + 1, i2*sU[e][1] + i0*vj[1]);
        atomicAdd(dvp + 2, i2*sU[e][2] + i0*vj[2]);
    }
}

} // anonymous namespace

extern "C" void kernel_launch(void* const* d_in, const int* in_sizes, int n_in,
                              void* d_out, int out_size, void* d_ws, size_t ws_size,
                              hipStream_t stream)
{
    const float* s_j  = (const float*)d_in[0];
    const float* v_j  = (const float*)d_in[1];
    const float* r_ij = (const float*)d_in[2];
    const int*   nbrs = (const int*)d_in[3];
    const float* W1   = (const float*)d_in[4];
    const float* b1   = (const float*)d_in[5];
    const float* W2   = (const float*)d_in[6];
    const float* b2   = (const float*)d_in[7];
    const float* Wd   = (const float*)d_in[8];
    const float* bd   = (const float*)d_in[9];

    float* ds_out = (float*)d_out;
    float* dv_out = ds_out + (size_t)NNODES * FEAT;
    short* pw     = (short*)d_ws;

    hipMemsetAsync(d_out, 0, (size_t)out_size * sizeof(float), stream);

    prep_kernel<<<(PT_TOTAL + 255)/256, 256, 0, stream>>>(W1, W2, Wd, pw);

    msg_kernel<<<NBLK, 256, 0, stream>>>(
        s_j, v_j, r_ij, nbrs, b1, b2, bd, pw, ds_out, dv_out);
}

// Round 5
// 486.393 us; speedup vs baseline: 3.9799x; 3.6127x over previous
//
#include <hip/hip_runtime.h>

namespace {

constexpr int FEAT   = 128;
constexpr int NRBF   = 20;
constexpr int EPB    = 32;        // edges per block
constexpr int NNODES = 25000;
constexpr int NEDGES = 400000;
constexpr int NBLK   = NEDGES / EPB;   // 12500
constexpr float PI_F = 3.14159265358979323846f;

using f32x4 = __attribute__((ext_vector_type(4))) float;
using s16x8 = __attribute__((ext_vector_type(8))) short;
using s16x4 = __attribute__((ext_vector_type(4))) short;

// packed-weight layout in d_ws (bf16 elements)
constexpr int PW1_ELEMS = 8  * 4 * 64 * 8;   // 16384
constexpr int PW2_ELEMS = 24 * 4 * 64 * 8;   // 49152
constexpr int PWD_ELEMS = 24 * 1 * 64 * 8;   // 12288
constexpr int PW1_OFF = 0;
constexpr int PW2_OFF = PW1_ELEMS;
constexpr int PWD_OFF = PW1_ELEMS + PW2_ELEMS;
constexpr int PT_TOTAL = PW1_ELEMS + PW2_ELEMS + PWD_ELEMS;  // 77824

__device__ inline unsigned short f2bf(float f) {
    unsigned u = __builtin_bit_cast(unsigned, f);
    u += 0x7fffu + ((u >> 16) & 1u);
    return (unsigned short)(u >> 16);
}
__device__ inline float bf2f(unsigned short h) {
    unsigned u = ((unsigned)h) << 16;
    return __builtin_bit_cast(float, u);
}

// ---- prep: pack W1/W2/Wd into per-lane MFMA B-fragment order (bf16) ----
__global__ __launch_bounds__(256) void prep_kernel(
    const float* __restrict__ W1, const float* __restrict__ W2,
    const float* __restrict__ Wd, short* __restrict__ pw)
{
    const int idx = blockIdx.x * 256 + threadIdx.x;
    if (idx >= PT_TOTAL) return;
    float val;
    if (idx < PW2_OFF) {
        const int t = idx;
        const int r = t & 7, lane = (t >> 3) & 63, ks = (t >> 9) & 3, nt = t >> 11;
        const int k = ks*32 + (lane>>4)*8 + r, n = nt*16 + (lane & 15);
        val = W1[k*128 + n];
    } else if (idx < PWD_OFF) {
        const int t = idx - PW2_OFF;
        const int r = t & 7, lane = (t >> 3) & 63, ks = (t >> 9) & 3, nt = t >> 11;
        const int k = ks*32 + (lane>>4)*8 + r, n = nt*16 + (lane & 15);
        val = W2[k*384 + n];
    } else {
        const int t = idx - PWD_OFF;
        const int r = t & 7, lane = (t >> 3) & 63, nt = t >> 9;
        const int k = (lane>>4)*8 + r, n = nt*16 + (lane & 15);
        val = (k < NRBF) ? Wd[k*384 + n] : 0.f;
    }
    pw[idx] = (short)f2bf(val);
}

// ---- counting-sort kernels: sort edge ids by dst ----
__global__ __launch_bounds__(256) void hist_kernel(
    const int* __restrict__ nbrs, int* __restrict__ hist)
{
    const int e = blockIdx.x * 256 + threadIdx.x;
    if (e >= NEDGES) return;
    atomicAdd(&hist[nbrs[2*e]], 1);
}

__global__ __launch_bounds__(256) void scan_kernel(
    const int* __restrict__ hist, int* __restrict__ cursor)
{
    __shared__ int part[256];
    const int t = threadIdx.x;
    constexpr int CH = (NNODES + 255) / 256;   // 98
    const int base = t * CH;
    int s = 0;
    for (int i = 0; i < CH; ++i) {
        const int idx = base + i;
        if (idx < NNODES) s += hist[idx];
    }
    part[t] = s;
    __syncthreads();
    for (int off = 1; off < 256; off <<= 1) {
        int v = part[t];
        if (t >= off) v += part[t - off];
        __syncthreads();
        part[t] = v;
        __syncthreads();
    }
    int run = part[t] - s;        // exclusive prefix of this thread's chunk
    for (int i = 0; i < CH; ++i) {
        const int idx = base + i;
        if (idx < NNODES) { cursor[idx] = run; run += hist[idx]; }
    }
}

__global__ __launch_bounds__(256) void scatter_kernel(
    const int* __restrict__ nbrs, int* __restrict__ cursor,
    int* __restrict__ eids)
{
    const int e = blockIdx.x * 256 + threadIdx.x;
    if (e >= NEDGES) return;
    const int dst = nbrs[2*e];
    const int pos = atomicAdd(&cursor[dst], 1);
    eids[pos] = e;
}

// ---- main fused kernel (edges pre-sorted by dst) ----
__global__ __launch_bounds__(256) void msg_kernel(
    const float* __restrict__ s_j, const float* __restrict__ v_j,
    const float* __restrict__ r_ij, const int* __restrict__ nbrs,
    const float* __restrict__ b1, const float* __restrict__ b2,
    const float* __restrict__ bd, const short* __restrict__ pw,
    const int* __restrict__ eids,
    float* __restrict__ ds_out, float* __restrict__ dv_out)
{
    // XOR-swizzled bf16 tiles: element (m,k) at [m*LD + (k ^ ((m&7)<<3))]
    __shared__ short sA[EPB * 128];      // gathered s rows        (8 KB)
    __shared__ short sH[EPB * 128];      // swish(s@W1+b1)         (8 KB)
    __shared__ short sR[EPB * 64];       // rbf, K=32 zero-padded  (4 KB)
    __shared__ short sI[EPB * 384];      // inv = phi*w_s          (24 KB)
    __shared__ float sU[EPB][3];
    __shared__ int   sSrc[EPB], sDst[EPB];

    const int tid = threadIdx.x;
    const int w   = tid >> 6;
    const int l   = tid & 63;
    const int mr  = l & 15;
    const int g   = l >> 4;
    const int e0  = blockIdx.x * EPB;

    // ---- P0a: per-edge meta ----
    if (tid < EPB) {
        const int eid = eids[e0 + tid];
        sDst[tid] = nbrs[2*eid + 0];
        sSrc[tid] = nbrs[2*eid + 1];
        const float r0 = r_ij[3*eid+0], r1 = r_ij[3*eid+1], r2 = r_ij[3*eid+2];
        const float d     = sqrtf(r0*r0 + r1*r1 + r2*r2 + 3e-15f);
        const float inv_d = 1.0f / d;
        sU[tid][0] = r0*inv_d; sU[tid][1] = r1*inv_d; sU[tid][2] = r2*inv_d;
        const int xr = (tid & 7) << 3;
        #pragma unroll
        for (int k = 0; k < 64; ++k) {
            const float v = (k < NRBF) ? __sinf((float)(k+1)*(PI_F/5.0f)*d)*inv_d : 0.f;
            sR[tid*64 + (k ^ xr)] = (short)f2bf(v);
        }
    }

    // ---- P0b: gather s_j rows -> bf16 LDS ----
    #pragma unroll
    for (int p = 0; p < 4; ++p) {
        const int v  = tid + p*256;
        const int e  = v >> 5;
        const int c4 = (v & 31) * 4;
        const int eid = eids[e0 + e];
        const int src = nbrs[2*eid + 1];
        const float4 f = reinterpret_cast<const float4*>(s_j + (size_t)src*FEAT)[v & 31];
        s16x4 h;
        h.x = (short)f2bf(f.x); h.y = (short)f2bf(f.y);
        h.z = (short)f2bf(f.z); h.w = (short)f2bf(f.w);
        *reinterpret_cast<s16x4*>(&sA[e*128 + (c4 ^ ((e & 7) << 3))]) = h;
    }
    __syncthreads();

    // ---- P1: GEMM1  h = swish(s@W1 + b1) ----
    {
        s16x8 aS[2][4];
        #pragma unroll
        for (int mt = 0; mt < 2; ++mt) {
            const int m = mt*16 + mr;
            const int xr = (m & 7) << 3;
            #pragma unroll
            for (int ks = 0; ks < 4; ++ks)
                aS[mt][ks] = *reinterpret_cast<const s16x8*>(&sA[m*128 + ((ks*32 + g*8) ^ xr)]);
        }
        const s16x8* pW1 = reinterpret_cast<const s16x8*>(pw + PW1_OFF);
        #pragma unroll
        for (int i = 0; i < 2; ++i) {
            const int nt = w*2 + i;
            const int n  = nt*16 + mr;
            const float b1n = b1[n];
            f32x4 acc[2] = {f32x4{0,0,0,0}, f32x4{0,0,0,0}};
            #pragma unroll
            for (int ks = 0; ks < 4; ++ks) {
                const s16x8 b = pW1[(nt*4 + ks)*64 + l];
                acc[0] = __builtin_amdgcn_mfma_f32_16x16x32_bf16(aS[0][ks], b, acc[0], 0, 0, 0);
                acc[1] = __builtin_amdgcn_mfma_f32_16x16x32_bf16(aS[1][ks], b, acc[1], 0, 0, 0);
            }
            #pragma unroll
            for (int mt = 0; mt < 2; ++mt)
                #pragma unroll
                for (int r = 0; r < 4; ++r) {
                    const int m = mt*16 + g*4 + r;
                    const float x = acc[mt][r] + b1n;
                    const float hsw = x / (1.0f + __expf(-x));
                    sH[m*128 + (n ^ ((m & 7) << 3))] = (short)f2bf(hsw);
                }
        }
    }
    __syncthreads();

    // ---- P2: phi = h@W2+b2 ; ws = rbf@Wd+bd ; inv = phi*ws ----
    {
        s16x8 aH[2][4], aR[2];
        #pragma unroll
        for (int mt = 0; mt < 2; ++mt) {
            const int m = mt*16 + mr;
            const int xr = (m & 7) << 3;
            #pragma unroll
            for (int ks = 0; ks < 4; ++ks)
                aH[mt][ks] = *reinterpret_cast<const s16x8*>(&sH[m*128 + ((ks*32 + g*8) ^ xr)]);
            aR[mt] = *reinterpret_cast<const s16x8*>(&sR[m*64 + ((g*8) ^ xr)]);
        }
        const s16x8* pW2 = reinterpret_cast<const s16x8*>(pw + PW2_OFF);
        const s16x8* pWd = reinterpret_cast<const s16x8*>(pw + PWD_OFF);
        #pragma unroll
        for (int i = 0; i < 6; ++i) {
            const int nt = w*6 + i;
            const int n  = nt*16 + mr;
            const float b2n = b2[n], bdn = bd[n];
            f32x4 acc[2]  = {f32x4{0,0,0,0}, f32x4{0,0,0,0}};
            f32x4 accw[2] = {f32x4{0,0,0,0}, f32x4{0,0,0,0}};
            #pragma unroll
            for (int ks = 0; ks < 4; ++ks) {
                const s16x8 b = pW2[(nt*4 + ks)*64 + l];
                acc[0] = __builtin_amdgcn_mfma_f32_16x16x32_bf16(aH[0][ks], b, acc[0], 0, 0, 0);
                acc[1] = __builtin_amdgcn_mfma_f32_16x16x32_bf16(aH[1][ks], b, acc[1], 0, 0, 0);
            }
            const s16x8 bw = pWd[nt*64 + l];
            accw[0] = __builtin_amdgcn_mfma_f32_16x16x32_bf16(aR[0], bw, accw[0], 0, 0, 0);
            accw[1] = __builtin_amdgcn_mfma_f32_16x16x32_bf16(aR[1], bw, accw[1], 0, 0, 0);
            #pragma unroll
            for (int mt = 0; mt < 2; ++mt)
                #pragma unroll
                for (int r = 0; r < 4; ++r) {
                    const int m = mt*16 + g*4 + r;
                    const float inv = (acc[mt][r] + b2n) * (accw[mt][r] + bdn);
                    sI[m*384 + n] = (short)f2bf(inv);
                }
        }
    }
    __syncthreads();

    // ---- P3: segmented scatter-add (edges sorted by dst) ----
    {
        const int half = tid >> 7;     // 0/1 -> edges [0..15] / [16..31]
        const int f    = tid & 127;
        const int eb   = half * 16;
        float accS = 0.f, a0 = 0.f, a1 = 0.f, a2 = 0.f;
        int cur = sDst[eb];
        #pragma unroll 4
        for (int e = eb; e < eb + 16; ++e) {
            const int d = sDst[e];
            if (d != cur) {
                atomicAdd(ds_out + (size_t)cur*FEAT + f, accS);
                float* dvp = dv_out + (size_t)cur*(3*FEAT) + 3*f;
                atomicAdd(dvp + 0, a0);
                atomicAdd(dvp + 1, a1);
                atomicAdd(dvp + 2, a2);
                accS = a0 = a1 = a2 = 0.f;
                cur = d;
            }
            const float i0 = bf2f((unsigned short)sI[e*384 + 3*f + 0]);
            const float i1 = bf2f((unsigned short)sI[e*384 + 3*f + 1]);
            const float i2 = bf2f((unsigned short)sI[e*384 + 3*f + 2]);
            const int src = sSrc[e];
            const float* vj = v_j + (size_t)src*(3*FEAT) + 3*f;
            const float u0 = sU[e][0], u1 = sU[e][1], u2 = sU[e][2];
            accS += i1;
            a0 += i2*u0 + i0*vj[0];
            a1 += i2*u1 + i0*vj[1];
            a2 += i2*u2 + i0*vj[2];
        }
        atomicAdd(ds_out + (size_t)cur*FEAT + f, accS);
        float* dvp = dv_out + (size_t)cur*(3*FEAT) + 3*f;
        atomicAdd(dvp + 0, a0);
        atomicAdd(dvp + 1, a1);
        atomicAdd(dvp + 2, a2);
    }
}

} // anonymous namespace

extern "C" void kernel_launch(void* const* d_in, const int* in_sizes, int n_in,
                              void* d_out, int out_size, void* d_ws, size_t ws_size,
                              hipStream_t stream)
{
    const float* s_j  = (const float*)d_in[0];
    const float* v_j  = (const float*)d_in[1];
    const float* r_ij = (const float*)d_in[2];
    const int*   nbrs = (const int*)d_in[3];
    const float* W1   = (const float*)d_in[4];
    const float* b1   = (const float*)d_in[5];
    const float* W2   = (const float*)d_in[6];
    const float* b2   = (const float*)d_in[7];
    const float* Wd   = (const float*)d_in[8];
    const float* bd   = (const float*)d_in[9];

    float* ds_out = (float*)d_out;
    float* dv_out = ds_out + (size_t)NNODES * FEAT;

    char* base   = (char*)d_ws;
    short* pw    = (short*)base;                       // 155,648 B
    int*  hist   = (int*)(base + 160*1024);            // 100,000 B
    int*  cursor = (int*)(base + 272*1024);            // 100,000 B
    int*  eids   = (int*)(base + 384*1024);            // 1,600,000 B

    hipMemsetAsync(d_out, 0, (size_t)out_size * sizeof(float), stream);
    hipMemsetAsync(hist, 0, NNODES * sizeof(int), stream);

    prep_kernel<<<(PT_TOTAL + 255)/256, 256, 0, stream>>>(W1, W2, Wd, pw);
    hist_kernel<<<(NEDGES + 255)/256, 256, 0, stream>>>(nbrs, hist);
    scan_kernel<<<1, 256, 0, stream>>>(hist, cursor);
    scatter_kernel<<<(NEDGES + 255)/256, 256, 0, stream>>>(nbrs, cursor, eids);

    msg_kernel<<<NBLK, 256, 0, stream>>>(
        s_j, v_j, r_ij, nbrs, b1, b2, bd, pw, eids, ds_out, dv_out);
}

// Round 6
// 438.171 us; speedup vs baseline: 4.4179x; 1.1101x over previous
//
#include <hip/hip_runtime.h>

namespace {

constexpr int FEAT   = 128;
constexpr int NRBF   = 20;
constexpr int EPB    = 32;        // edges per block
constexpr int NNODES = 25000;
constexpr int NEDGES = 400000;
constexpr int NBLK   = NEDGES / EPB;   // 12500
constexpr int NSCAN  = (NNODES + 255) / 256;  // 98
constexpr float PI_F = 3.14159265358979323846f;

using f32x4 = __attribute__((ext_vector_type(4))) float;
using s16x8 = __attribute__((ext_vector_type(8))) short;
using s16x4 = __attribute__((ext_vector_type(4))) short;

// packed-weight layout in d_ws (bf16 elements)
constexpr int PW1_ELEMS = 8  * 4 * 64 * 8;   // 16384
constexpr int PW2_ELEMS = 24 * 4 * 64 * 8;   // 49152
constexpr int PWD_ELEMS = 24 * 1 * 64 * 8;   // 12288
constexpr int PW1_OFF = 0;
constexpr int PW2_OFF = PW1_ELEMS;
constexpr int PWD_OFF = PW1_ELEMS + PW2_ELEMS;
constexpr int PT_TOTAL = PW1_ELEMS + PW2_ELEMS + PWD_ELEMS;  // 77824

__device__ inline unsigned short f2bf(float f) {
    unsigned u = __builtin_bit_cast(unsigned, f);
    u += 0x7fffu + ((u >> 16) & 1u);
    return (unsigned short)(u >> 16);
}
__device__ inline float bf2f(unsigned short h) {
    unsigned u = ((unsigned)h) << 16;
    return __builtin_bit_cast(float, u);
}

// ---- prep: pack W1/W2/Wd into per-lane MFMA B-fragment order (bf16) ----
// W2/Wd columns are PERMUTED into 3 planes: packed col n in [0,384):
// plane c = n>>7, feat f = n&127, original col = 3*f + c.
__global__ __launch_bounds__(256) void prep_kernel(
    const float* __restrict__ W1, const float* __restrict__ W2,
    const float* __restrict__ Wd, short* __restrict__ pw)
{
    const int idx = blockIdx.x * 256 + threadIdx.x;
    if (idx >= PT_TOTAL) return;
    float val;
    if (idx < PW2_OFF) {
        const int t = idx;
        const int r = t & 7, lane = (t >> 3) & 63, ks = (t >> 9) & 3, nt = t >> 11;
        const int k = ks*32 + (lane>>4)*8 + r, n = nt*16 + (lane & 15);
        val = W1[k*128 + n];
    } else if (idx < PWD_OFF) {
        const int t = idx - PW2_OFF;
        const int r = t & 7, lane = (t >> 3) & 63, ks = (t >> 9) & 3, nt = t >> 11;
        const int k = ks*32 + (lane>>4)*8 + r, n = nt*16 + (lane & 15);
        const int orig = 3*(n & 127) + (n >> 7);
        val = W2[k*384 + orig];
    } else {
        const int t = idx - PWD_OFF;
        const int r = t & 7, lane = (t >> 3) & 63, nt = t >> 9;
        const int k = (lane>>4)*8 + r, n = nt*16 + (lane & 15);
        const int orig = 3*(n & 127) + (n >> 7);
        val = (k < NRBF) ? Wd[k*384 + orig] : 0.f;
    }
    pw[idx] = (short)f2bf(val);
}

// ---- counting-sort kernels: sort edge ids by dst ----
__global__ __launch_bounds__(256) void hist_kernel(
    const int* __restrict__ nbrs, int* __restrict__ hist)
{
    const int e = blockIdx.x * 256 + threadIdx.x;
    if (e >= NEDGES) return;
    const int2 nb = reinterpret_cast<const int2*>(nbrs)[e];
    atomicAdd(&hist[nb.x], 1);
}

// hierarchical scan: A (per-block local excl scan + block sum),
// B (scan of 98 block sums), C (add back)
__global__ __launch_bounds__(256) void scanA_kernel(
    const int* __restrict__ hist, int* __restrict__ cursor, int* __restrict__ bsum)
{
    __shared__ int sh[256];
    const int t = threadIdx.x, idx = blockIdx.x*256 + t;
    const int v = (idx < NNODES) ? hist[idx] : 0;
    sh[t] = v; __syncthreads();
    int acc = v;
    for (int off = 1; off < 256; off <<= 1) {
        const int add = (t >= off) ? sh[t-off] : 0;
        __syncthreads();
        acc += add; sh[t] = acc;
        __syncthreads();
    }
    if (idx < NNODES) cursor[idx] = acc - v;    // exclusive
    if (t == 255) bsum[blockIdx.x] = acc;
}

__global__ __launch_bounds__(128) void scanB_kernel(
    const int* __restrict__ bsum, int* __restrict__ boffs)
{
    __shared__ int sh[128];
    const int t = threadIdx.x;
    const int v = (t < NSCAN) ? bsum[t] : 0;
    sh[t] = v; __syncthreads();
    int acc = v;
    for (int off = 1; off < 128; off <<= 1) {
        const int add = (t >= off) ? sh[t-off] : 0;
        __syncthreads();
        acc += add; sh[t] = acc;
        __syncthreads();
    }
    if (t < NSCAN) boffs[t] = acc - v;          // exclusive
}

__global__ __launch_bounds__(256) void scanC_kernel(
    int* __restrict__ cursor, const int* __restrict__ boffs)
{
    const int idx = blockIdx.x*256 + threadIdx.x;
    if (idx < NNODES) cursor[idx] += boffs[blockIdx.x];
}

__global__ __launch_bounds__(256) void scatter_kernel(
    const int* __restrict__ nbrs, int* __restrict__ cursor,
    int* __restrict__ eids)
{
    const int e = blockIdx.x * 256 + threadIdx.x;
    if (e >= NEDGES) return;
    const int dst = nbrs[2*e];
    const int pos = atomicAdd(&cursor[dst], 1);
    eids[pos] = e;
}

// ---- main fused kernel (edges pre-sorted by dst) ----
// LDS overlay: one 24 KB tile region.
//   phase A/B: sA [0,4096) sH [4096,8192) sR [8192,10240)  (shorts)
//   phase C:   inv planes c*4096 + e*128 + f   (3 x 4096 shorts)
// All tiles XOR-swizzled: elem (row, col) at [row*LD + (col ^ ((row&7)<<3))]
__global__ __launch_bounds__(256) void msg_kernel(
    const float* __restrict__ s_j, const float* __restrict__ v_j,
    const float* __restrict__ r_ij, const int* __restrict__ nbrs,
    const float* __restrict__ b1, const float* __restrict__ b2,
    const float* __restrict__ bd, const short* __restrict__ pw,
    const int* __restrict__ eids,
    float* __restrict__ ds_out, float* __restrict__ dv_out)
{
    __shared__ short sTile[12288];       // 24 KB
    __shared__ float sU[EPB][3];
    __shared__ int   sSrc[EPB], sDst[EPB];
    constexpr int OFF_A = 0, OFF_H = 4096, OFF_R = 8192;

    const int tid = threadIdx.x;
    const int w   = tid >> 6;
    const int l   = tid & 63;
    const int mr  = l & 15;
    const int g   = l >> 4;
    const int e0  = blockIdx.x * EPB;

    // ---- P0a: per-edge meta, 8 threads per edge ----
    {
        const int ep  = tid >> 3;        // edge 0..31
        const int sub = tid & 7;
        const int eid = eids[e0 + ep];
        const int2 nb = reinterpret_cast<const int2*>(nbrs)[eid];
        const float r0 = r_ij[3*eid+0], r1 = r_ij[3*eid+1], r2 = r_ij[3*eid+2];
        const float d     = sqrtf(r0*r0 + r1*r1 + r2*r2 + 3e-15f);
        const float inv_d = 1.0f / d;
        if (sub == 0) {
            sDst[ep] = nb.x; sSrc[ep] = nb.y;
            sU[ep][0] = r0*inv_d; sU[ep][1] = r1*inv_d; sU[ep][2] = r2*inv_d;
        }
        s16x8 rv;
        #pragma unroll
        for (int kk = 0; kk < 8; ++kk) {
            const int k = sub*8 + kk;
            const float v = (k < NRBF) ? __sinf((float)(k+1)*(PI_F/5.0f)*d)*inv_d : 0.f;
            rv[kk] = (short)f2bf(v);
        }
        *reinterpret_cast<s16x8*>(&sTile[OFF_R + ep*64 + ((sub*8) ^ ((ep & 7) << 3))]) = rv;
    }

    // ---- P0b: gather s_j rows -> bf16 LDS ----
    #pragma unroll
    for (int p = 0; p < 4; ++p) {
        const int v  = tid + p*256;
        const int e  = v >> 5;
        const int c4 = (v & 31) * 4;
        const int eid = eids[e0 + e];
        const int src = nbrs[2*eid + 1];
        const float4 f = reinterpret_cast<const float4*>(s_j + (size_t)src*FEAT)[v & 31];
        s16x4 h;
        h.x = (short)f2bf(f.x); h.y = (short)f2bf(f.y);
        h.z = (short)f2bf(f.z); h.w = (short)f2bf(f.w);
        *reinterpret_cast<s16x4*>(&sTile[OFF_A + e*128 + (c4 ^ ((e & 7) << 3))]) = h;
    }
    __syncthreads();

    // ---- P1: GEMM1  h = swish(s@W1 + b1) ----
    {
        s16x8 aS[2][4];
        #pragma unroll
        for (int mt = 0; mt < 2; ++mt) {
            const int m = mt*16 + mr;
            const int xr = (m & 7) << 3;
            #pragma unroll
            for (int ks = 0; ks < 4; ++ks)
                aS[mt][ks] = *reinterpret_cast<const s16x8*>(&sTile[OFF_A + m*128 + ((ks*32 + g*8) ^ xr)]);
        }
        const s16x8* pW1 = reinterpret_cast<const s16x8*>(pw + PW1_OFF);
        #pragma unroll
        for (int i = 0; i < 2; ++i) {
            const int nt = w*2 + i;
            const int n  = nt*16 + mr;
            const float b1n = b1[n];
            f32x4 acc[2] = {f32x4{0,0,0,0}, f32x4{0,0,0,0}};
            #pragma unroll
            for (int ks = 0; ks < 4; ++ks) {
                const s16x8 b = pW1[(nt*4 + ks)*64 + l];
                acc[0] = __builtin_amdgcn_mfma_f32_16x16x32_bf16(aS[0][ks], b, acc[0], 0, 0, 0);
                acc[1] = __builtin_amdgcn_mfma_f32_16x16x32_bf16(aS[1][ks], b, acc[1], 0, 0, 0);
            }
            #pragma unroll
            for (int mt = 0; mt < 2; ++mt)
                #pragma unroll
                for (int r = 0; r < 4; ++r) {
                    const int m = mt*16 + g*4 + r;
                    const float x = acc[mt][r] + b1n;
                    const float hsw = x / (1.0f + __expf(-x));
                    sTile[OFF_H + m*128 + (n ^ ((m & 7) << 3))] = (short)f2bf(hsw);
                }
        }
    }
    __syncthreads();

    // ---- P2: phi = h@W2+b2 ; ws = rbf@Wd+bd ; inv = phi*ws -> 3 planes ----
    {
        s16x8 aH[2][4], aR[2];
        #pragma unroll
        for (int mt = 0; mt < 2; ++mt) {
            const int m = mt*16 + mr;
            const int xr = (m & 7) << 3;
            #pragma unroll
            for (int ks = 0; ks < 4; ++ks)
                aH[mt][ks] = *reinterpret_cast<const s16x8*>(&sTile[OFF_H + m*128 + ((ks*32 + g*8) ^ xr)]);
            aR[mt] = *reinterpret_cast<const s16x8*>(&sTile[OFF_R + m*64 + ((g*8) ^ xr)]);
        }
        __syncthreads();   // all reads of sA/sH/sR done; tile becomes inv planes

        const s16x8* pW2 = reinterpret_cast<const s16x8*>(pw + PW2_OFF);
        const s16x8* pWd = reinterpret_cast<const s16x8*>(pw + PWD_OFF);
        #pragma unroll
        for (int i = 0; i < 6; ++i) {
            const int nt = w*6 + i;
            const int n  = nt*16 + mr;            // packed col 0..383
            const int c  = n >> 7;                // plane
            const int f2 = n & 127;               // feature
            const int orig = 3*f2 + c;            // original col for biases
            const float b2n = b2[orig], bdn = bd[orig];
            f32x4 acc[2]  = {f32x4{0,0,0,0}, f32x4{0,0,0,0}};
            f32x4 accw[2] = {f32x4{0,0,0,0}, f32x4{0,0,0,0}};
            #pragma unroll
            for (int ks = 0; ks < 4; ++ks) {
                const s16x8 b = pW2[(nt*4 + ks)*64 + l];
                acc[0] = __builtin_amdgcn_mfma_f32_16x16x32_bf16(aH[0][ks], b, acc[0], 0, 0, 0);
                acc[1] = __builtin_amdgcn_mfma_f32_16x16x32_bf16(aH[1][ks], b, acc[1], 0, 0, 0);
            }
            const s16x8 bw = pWd[nt*64 + l];
            accw[0] = __builtin_amdgcn_mfma_f32_16x16x32_bf16(aR[0], bw, accw[0], 0, 0, 0);
            accw[1] = __builtin_amdgcn_mfma_f32_16x16x32_bf16(aR[1], bw, accw[1], 0, 0, 0);
            #pragma unroll
            for (int mt = 0; mt < 2; ++mt)
                #pragma unroll
                for (int r = 0; r < 4; ++r) {
                    const int m = mt*16 + g*4 + r;
                    const float inv = (acc[mt][r] + b2n) * (accw[mt][r] + bdn);
                    sTile[c*4096 + m*128 + (f2 ^ ((m & 7) << 3))] = (short)f2bf(inv);
                }
        }
    }
    __syncthreads();

    // ---- P3: segmented scatter-add (edges sorted by dst) ----
    {
        const int half = tid >> 7;     // 0/1 -> edges [0..15] / [16..31]
        const int f    = tid & 127;
        const int eb   = half * 16;
        float accS = 0.f, a0 = 0.f, a1 = 0.f, a2 = 0.f;
        int cur = sDst[eb];
        #pragma unroll 4
        for (int e = eb; e < eb + 16; ++e) {
            const int d = sDst[e];
            if (d != cur) {
                atomicAdd(ds_out + (size_t)cur*FEAT + f, accS);
                float* dvp = dv_out + (size_t)cur*(3*FEAT) + 3*f;
                atomicAdd(dvp + 0, a0);
                atomicAdd(dvp + 1, a1);
                atomicAdd(dvp + 2, a2);
                accS = a0 = a1 = a2 = 0.f;
                cur = d;
            }
            const int fx = f ^ ((e & 7) << 3);
            const float i0 = bf2f((unsigned short)sTile[        e*128 + fx]);
            const float i1 = bf2f((unsigned short)sTile[4096 + e*128 + fx]);
            const float i2 = bf2f((unsigned short)sTile[8192 + e*128 + fx]);
            const int src = sSrc[e];
            const float* vj = v_j + (size_t)src*(3*FEAT) + 3*f;
            const float u0 = sU[e][0], u1 = sU[e][1], u2 = sU[e][2];
            accS += i1;
            a0 += i2*u0 + i0*vj[0];
            a1 += i2*u1 + i0*vj[1];
            a2 += i2*u2 + i0*vj[2];
        }
        atomicAdd(ds_out + (size_t)cur*FEAT + f, accS);
        float* dvp = dv_out + (size_t)cur*(3*FEAT) + 3*f;
        atomicAdd(dvp + 0, a0);
        atomicAdd(dvp + 1, a1);
        atomicAdd(dvp + 2, a2);
    }
}

} // anonymous namespace

extern "C" void kernel_launch(void* const* d_in, const int* in_sizes, int n_in,
                              void* d_out, int out_size, void* d_ws, size_t ws_size,
                              hipStream_t stream)
{
    const float* s_j  = (const float*)d_in[0];
    const float* v_j  = (const float*)d_in[1];
    const float* r_ij = (const float*)d_in[2];
    const int*   nbrs = (const int*)d_in[3];
    const float* W1   = (const float*)d_in[4];
    const float* b1   = (const float*)d_in[5];
    const float* W2   = (const float*)d_in[6];
    const float* b2   = (const float*)d_in[7];
    const float* Wd   = (const float*)d_in[8];
    const float* bd   = (const float*)d_in[9];

    float* ds_out = (float*)d_out;
    float* dv_out = ds_out + (size_t)NNODES * FEAT;

    char* base   = (char*)d_ws;
    short* pw    = (short*)base;                       // 155,648 B
    int*  hist   = (int*)(base + 160*1024);            // 100,000 B
    int*  cursor = (int*)(base + 272*1024);            // 100,000 B
    int*  bsum   = (int*)(base + 376*1024);            // 392 B
    int*  boffs  = (int*)(base + 380*1024);            // 392 B
    int*  eids   = (int*)(base + 384*1024);            // 1,600,000 B

    hipMemsetAsync(d_out, 0, (size_t)out_size * sizeof(float), stream);
    hipMemsetAsync(hist, 0, NNODES * sizeof(int), stream);

    prep_kernel<<<(PT_TOTAL + 255)/256, 256, 0, stream>>>(W1, W2, Wd, pw);
    hist_kernel<<<(NEDGES + 255)/256, 256, 0, stream>>>(nbrs, hist);
    scanA_kernel<<<NSCAN, 256, 0, stream>>>(hist, cursor, bsum);
    scanB_kernel<<<1, 128, 0, stream>>>(bsum, boffs);
    scanC_kernel<<<NSCAN, 256, 0, stream>>>(cursor, boffs);
    scatter_kernel<<<(NEDGES + 255)/256, 256, 0, stream>>>(nbrs, cursor, eids);

    msg_kernel<<<NBLK, 256, 0, stream>>>(
        s_j, v_j, r_ij, nbrs, b1, b2, bd, pw, eids, ds_out, dv_out);
}

// Round 10
// 408.606 us; speedup vs baseline: 4.7376x; 1.0724x over previous
//
#include <hip/hip_runtime.h>

namespace {

constexpr int FEAT   = 128;
constexpr int NRBF   = 20;
constexpr int EPB    = 32;        // edges per block
constexpr int NNODES = 25000;
constexpr int NEDGES = 400000;
constexpr int NBLK   = NEDGES / EPB;        // 12500
constexpr int NPBLK  = (NNODES + 31) / 32;  // 782
constexpr int NSCAN  = (NNODES + 255) / 256;  // 98
constexpr float PI_F = 3.14159265358979323846f;

using f32x4 = __attribute__((ext_vector_type(4))) float;
using s16x8 = __attribute__((ext_vector_type(8))) short;
using s16x4 = __attribute__((ext_vector_type(4))) short;

// packed-weight layout (bf16 elements)
constexpr int PW1_ELEMS = 8  * 4 * 64 * 8;   // 16384
constexpr int PW2_ELEMS = 24 * 4 * 64 * 8;   // 49152
constexpr int PWD_ELEMS = 24 * 1 * 64 * 8;   // 12288
constexpr int PW1_OFF = 0;
constexpr int PW2_OFF = PW1_ELEMS;
constexpr int PWD_OFF = PW1_ELEMS + PW2_ELEMS;
constexpr int PT_TOTAL = PW1_ELEMS + PW2_ELEMS + PWD_ELEMS;  // 77824

__device__ inline unsigned short f2bf(float f) {
    unsigned u = __builtin_bit_cast(unsigned, f);
    u += 0x7fffu + ((u >> 16) & 1u);
    return (unsigned short)(u >> 16);
}
__device__ inline float bf2f(unsigned short h) {
    unsigned u = ((unsigned)h) << 16;
    return __builtin_bit_cast(float, u);
}

// ---- prep: pack W1/W2/Wd into per-lane MFMA B-fragment order (bf16) ----
// W2/Wd columns PERMUTED into 3 planes: packed col n: plane c=n>>7, f=n&127,
// original col = 3*f + c.
__global__ __launch_bounds__(256) void prep_kernel(
    const float* __restrict__ W1, const float* __restrict__ W2,
    const float* __restrict__ Wd, short* __restrict__ pw)
{
    const int idx = blockIdx.x * 256 + threadIdx.x;
    if (idx >= PT_TOTAL) return;
    float val;
    if (idx < PW2_OFF) {
        const int t = idx;
        const int r = t & 7, lane = (t >> 3) & 63, ks = (t >> 9) & 3, nt = t >> 11;
        const int k = ks*32 + (lane>>4)*8 + r, n = nt*16 + (lane & 15);
        val = W1[k*128 + n];
    } else if (idx < PWD_OFF) {
        const int t = idx - PW2_OFF;
        const int r = t & 7, lane = (t >> 3) & 63, ks = (t >> 9) & 3, nt = t >> 11;
        const int k = ks*32 + (lane>>4)*8 + r, n = nt*16 + (lane & 15);
        const int orig = 3*(n & 127) + (n >> 7);
        val = W2[k*384 + orig];
    } else {
        const int t = idx - PWD_OFF;
        const int r = t & 7, lane = (t >> 3) & 63, nt = t >> 9;
        const int k = (lane>>4)*8 + r, n = nt*16 + (lane & 15);
        const int orig = 3*(n & 127) + (n >> 7);
        val = (k < NRBF) ? Wd[k*384 + orig] : 0.f;
    }
    pw[idx] = (short)f2bf(val);
}

// ---- node-phi GEMM: phiT[c][node][f] = (swish(s_j@W1+b1)@W2+b2) permuted ----
__global__ __launch_bounds__(256) void nodephi_kernel(
    const float* __restrict__ s_j, const float* __restrict__ b1,
    const float* __restrict__ b2, const short* __restrict__ pw,
    unsigned short* __restrict__ phiT)
{
    __shared__ short sT[8192];           // sA [0,4096), sH [4096,8192)
    constexpr int OFF_H = 4096;
    const int tid = threadIdx.x;
    const int w   = tid >> 6;
    const int l   = tid & 63;
    const int mr  = l & 15;
    const int g   = l >> 4;
    const int n0  = blockIdx.x * 32;

    // P0: coalesced load of 32 node rows -> bf16 LDS (zero-pad past NNODES)
    #pragma unroll
    for (int p = 0; p < 4; ++p) {
        const int v  = tid + p*256;
        const int e  = v >> 5;
        const int c4 = (v & 31) * 4;
        const int node = n0 + e;
        float4 f = {0.f, 0.f, 0.f, 0.f};
        if (node < NNODES)
            f = reinterpret_cast<const float4*>(s_j + (size_t)node*FEAT)[v & 31];
        s16x4 h;
        h.x = (short)f2bf(f.x); h.y = (short)f2bf(f.y);
        h.z = (short)f2bf(f.z); h.w = (short)f2bf(f.w);
        *reinterpret_cast<s16x4*>(&sT[e*128 + (c4 ^ ((e & 7) << 3))]) = h;
    }
    __syncthreads();

    // P1: h = swish(s@W1+b1)
    {
        s16x8 aS[2][4];
        #pragma unroll
        for (int mt = 0; mt < 2; ++mt) {
            const int m = mt*16 + mr;
            const int xr = (m & 7) << 3;
            #pragma unroll
            for (int ks = 0; ks < 4; ++ks)
                aS[mt][ks] = *reinterpret_cast<const s16x8*>(&sT[m*128 + ((ks*32 + g*8) ^ xr)]);
        }
        const s16x8* pW1 = reinterpret_cast<const s16x8*>(pw + PW1_OFF);
        #pragma unroll
        for (int i = 0; i < 2; ++i) {
            const int nt = w*2 + i;
            const int n  = nt*16 + mr;
            const float b1n = b1[n];
            f32x4 acc[2] = {f32x4{0,0,0,0}, f32x4{0,0,0,0}};
            #pragma unroll
            for (int ks = 0; ks < 4; ++ks) {
                const s16x8 b = pW1[(nt*4 + ks)*64 + l];
                acc[0] = __builtin_amdgcn_mfma_f32_16x16x32_bf16(aS[0][ks], b, acc[0], 0, 0, 0);
                acc[1] = __builtin_amdgcn_mfma_f32_16x16x32_bf16(aS[1][ks], b, acc[1], 0, 0, 0);
            }
            #pragma unroll
            for (int mt = 0; mt < 2; ++mt)
                #pragma unroll
                for (int r = 0; r < 4; ++r) {
                    const int m = mt*16 + g*4 + r;
                    const float x = acc[mt][r] + b1n;
                    const float hsw = x / (1.0f + __expf(-x));
                    sT[OFF_H + m*128 + (n ^ ((m & 7) << 3))] = (short)f2bf(hsw);
                }
        }
    }
    __syncthreads();

    // P2: phi = h@W2+b2 -> global phi planes (bf16)
    {
        s16x8 aH[2][4];
        #pragma unroll
        for (int mt = 0; mt < 2; ++mt) {
            const int m = mt*16 + mr;
            const int xr = (m & 7) << 3;
            #pragma unroll
            for (int ks = 0; ks < 4; ++ks)
                aH[mt][ks] = *reinterpret_cast<const s16x8*>(&sT[OFF_H + m*128 + ((ks*32 + g*8) ^ xr)]);
        }
        const s16x8* pW2 = reinterpret_cast<const s16x8*>(pw + PW2_OFF);
        #pragma unroll
        for (int i = 0; i < 6; ++i) {
            const int nt = w*6 + i;
            const int n  = nt*16 + mr;            // packed col
            const int c  = n >> 7;
            const int f2 = n & 127;
            const float b2n = b2[3*f2 + c];
            f32x4 acc[2] = {f32x4{0,0,0,0}, f32x4{0,0,0,0}};
            #pragma unroll
            for (int ks = 0; ks < 4; ++ks) {
                const s16x8 b = pW2[(nt*4 + ks)*64 + l];
                acc[0] = __builtin_amdgcn_mfma_f32_16x16x32_bf16(aH[0][ks], b, acc[0], 0, 0, 0);
                acc[1] = __builtin_amdgcn_mfma_f32_16x16x32_bf16(aH[1][ks], b, acc[1], 0, 0, 0);
            }
            #pragma unroll
            for (int mt = 0; mt < 2; ++mt)
                #pragma unroll
                for (int r = 0; r < 4; ++r) {
                    const int m = mt*16 + g*4 + r;
                    const int node = n0 + m;
                    if (node < NNODES)
                        phiT[(size_t)c*NNODES*FEAT + (size_t)node*FEAT + f2] =
                            f2bf(acc[mt][r] + b2n);
                }
        }
    }
}

// ---- counting-sort kernels: sort edges by dst, emit packed records ----
__global__ __launch_bounds__(256) void hist_kernel(
    const int* __restrict__ nbrs, int* __restrict__ hist)
{
    const int e = blockIdx.x * 256 + threadIdx.x;
    if (e >= NEDGES) return;
    const int2 nb = reinterpret_cast<const int2*>(nbrs)[e];
    atomicAdd(&hist[nb.x], 1);
}

__global__ __launch_bounds__(256) void scanA_kernel(
    const int* __restrict__ hist, int* __restrict__ cursor, int* __restrict__ bsum)
{
    __shared__ int sh[256];
    const int t = threadIdx.x, idx = blockIdx.x*256 + t;
    const int v = (idx < NNODES) ? hist[idx] : 0;
    sh[t] = v; __syncthreads();
    int acc = v;
    for (int off = 1; off < 256; off <<= 1) {
        const int add = (t >= off) ? sh[t-off] : 0;
        __syncthreads();
        acc += add; sh[t] = acc;
        __syncthreads();
    }
    if (idx < NNODES) cursor[idx] = acc - v;
    if (t == 255) bsum[blockIdx.x] = acc;
}

__global__ __launch_bounds__(128) void scanB_kernel(
    const int* __restrict__ bsum, int* __restrict__ boffs)
{
    __shared__ int sh[128];
    const int t = threadIdx.x;
    const int v = (t < NSCAN) ? bsum[t] : 0;
    sh[t] = v; __syncthreads();
    int acc = v;
    for (int off = 1; off < 128; off <<= 1) {
        const int add = (t >= off) ? sh[t-off] : 0;
        __syncthreads();
        acc += add; sh[t] = acc;
        __syncthreads();
    }
    if (t < NSCAN) boffs[t] = acc - v;
}

__global__ __launch_bounds__(256) void scanC_kernel(
    int* __restrict__ cursor, const int* __restrict__ boffs)
{
    const int idx = blockIdx.x*256 + threadIdx.x;
    if (idx < NNODES) cursor[idx] += boffs[blockIdx.x];
}

__global__ __launch_bounds__(256) void scatter_kernel(
    const int* __restrict__ nbrs, const float* __restrict__ r_ij,
    int* __restrict__ cursor, int2* __restrict__ recDS, float4* __restrict__ recR)
{
    const int e = blockIdx.x * 256 + threadIdx.x;
    if (e >= NEDGES) return;
    const int2 nb = reinterpret_cast<const int2*>(nbrs)[e];
    const int pos = atomicAdd(&cursor[nb.x], 1);
    recDS[pos] = nb;
    recR[pos] = make_float4(r_ij[3*e+0], r_ij[3*e+1], r_ij[3*e+2], 0.f);
}

// ---- edge kernel (records pre-sorted by dst) ----
// LDS: inv/phi planes [0,12288) shorts, sR [12288,14336)
__global__ __launch_bounds__(256) void msg_kernel(
    const float* __restrict__ v_j, const int2* __restrict__ recDS,
    const float4* __restrict__ recR, const float* __restrict__ bd,
    const short* __restrict__ pw, const unsigned short* __restrict__ phiT,
    float* __restrict__ ds_out, float* __restrict__ dv_out)
{
    __shared__ short sP[14336];          // 28 KB
    __shared__ float sU[EPB][3];
    __shared__ int   sSrc[EPB], sDst[EPB];
    constexpr int OFF_R = 12288;

    const int tid = threadIdx.x;
    const int w   = tid >> 6;
    const int l   = tid & 63;
    const int mr  = l & 15;
    const int g   = l >> 4;
    const int e0  = blockIdx.x * EPB;

    // P0a: per-edge meta, 8 threads per edge (coalesced record reads)
    {
        const int ep  = tid >> 3;
        const int sub = tid & 7;
        const int2  nb = recDS[e0 + ep];
        const float4 r = recR[e0 + ep];
        const float d     = sqrtf(r.x*r.x + r.y*r.y + r.z*r.z + 3e-15f);
        const float inv_d = 1.0f / d;
        if (sub == 0) {
            sDst[ep] = nb.x; sSrc[ep] = nb.y;
            sU[ep][0] = r.x*inv_d; sU[ep][1] = r.y*inv_d; sU[ep][2] = r.z*inv_d;
        }
        s16x8 rv;
        #pragma unroll
        for (int kk = 0; kk < 8; ++kk) {
            const int k = sub*8 + kk;
            const float v = (k < NRBF) ? __sinf((float)(k+1)*(PI_F/5.0f)*d)*inv_d : 0.f;
            rv[kk] = (short)f2bf(v);
        }
        *reinterpret_cast<s16x8*>(&sP[OFF_R + ep*64 + ((sub*8) ^ ((ep & 7) << 3))]) = rv;
    }

    // P0b: gather phi plane rows (bf16, 16B chunks) -> LDS planes
    #pragma unroll
    for (int pl = 0; pl < 3; ++pl) {
        #pragma unroll
        for (int p = 0; p < 2; ++p) {
            const int v  = tid + p*256;        // 0..511
            const int e  = v >> 4;
            const int ch = (v & 15) * 8;       // bf16 elem offset in row
            const int src = recDS[e0 + e].y;
            const s16x8 val = *reinterpret_cast<const s16x8*>(
                phiT + (size_t)pl*NNODES*FEAT + (size_t)src*FEAT + ch);
            *reinterpret_cast<s16x8*>(&sP[pl*4096 + e*128 + (ch ^ ((e & 7) << 3))]) = val;
        }
    }
    __syncthreads();

    // P2: ws = rbf@Wd+bd (MFMA); inv = phi*ws in-place in LDS planes
    {
        s16x8 aR[2];
        #pragma unroll
        for (int mt = 0; mt < 2; ++mt) {
            const int m = mt*16 + mr;
            aR[mt] = *reinterpret_cast<const s16x8*>(&sP[OFF_R + m*64 + ((g*8) ^ ((m & 7) << 3))]);
        }
        const s16x8* pWd = reinterpret_cast<const s16x8*>(pw + PWD_OFF);
        #pragma unroll
        for (int i = 0; i < 6; ++i) {
            const int nt = w*6 + i;
            const int n  = nt*16 + mr;            // packed col
            const int c  = n >> 7;
            const int f2 = n & 127;
            const float bdn = bd[3*f2 + c];
            const s16x8 bw = pWd[nt*64 + l];
            f32x4 accw[2] = {f32x4{0,0,0,0}, f32x4{0,0,0,0}};
            accw[0] = __builtin_amdgcn_mfma_f32_16x16x32_bf16(aR[0], bw, accw[0], 0, 0, 0);
            accw[1] = __builtin_amdgcn_mfma_f32_16x16x32_bf16(aR[1], bw, accw[1], 0, 0, 0);
            #pragma unroll
            for (int mt = 0; mt < 2; ++mt)
                #pragma unroll
                for (int r = 0; r < 4; ++r) {
                    const int m = mt*16 + g*4 + r;
                    const int addr = c*4096 + m*128 + (f2 ^ ((m & 7) << 3));
                    const float phi = bf2f((unsigned short)sP[addr]);
                    sP[addr] = (short)f2bf(phi * (accw[mt][r] + bdn));
                }
        }
    }
    __syncthreads();

    // P3: segmented scatter-add (edges sorted by dst)
    {
        const int half = tid >> 7;
        const int f    = tid & 127;
        const int eb   = half * 16;
        float accS = 0.f, a0 = 0.f, a1 = 0.f, a2 = 0.f;
        int cur = sDst[eb];
        #pragma unroll 4
        for (int e = eb; e < eb + 16; ++e) {
            const int d = sDst[e];
            if (d != cur) {
                atomicAdd(ds_out + (size_t)cur*FEAT + f, accS);
                float* dvp = dv_out + (size_t)cur*(3*FEAT) + 3*f;
                atomicAdd(dvp + 0, a0);
                atomicAdd(dvp + 1, a1);
                atomicAdd(dvp + 2, a2);
                accS = a0 = a1 = a2 = 0.f;
                cur = d;
            }
            const int fx = f ^ ((e & 7) << 3);
            const float i0 = bf2f((unsigned short)sP[        e*128 + fx]);
            const float i1 = bf2f((unsigned short)sP[4096 + e*128 + fx]);
            const float i2 = bf2f((unsigned short)sP[8192 + e*128 + fx]);
            const int src = sSrc[e];
            const float* vj = v_j + (size_t)src*(3*FEAT) + 3*f;
            const float u0 = sU[e][0], u1 = sU[e][1], u2 = sU[e][2];
            accS += i1;
            a0 += i2*u0 + i0*vj[0];
            a1 += i2*u1 + i0*vj[1];
            a2 += i2*u2 + i0*vj[2];
        }
        atomicAdd(ds_out + (size_t)cur*FEAT + f, accS);
        float* dvp = dv_out + (size_t)cur*(3*FEAT) + 3*f;
        atomicAdd(dvp + 0, a0);
        atomicAdd(dvp + 1, a1);
        atomicAdd(dvp + 2, a2);
    }
}

} // anonymous namespace

extern "C" void kernel_launch(void* const* d_in, const int* in_sizes, int n_in,
                              void* d_out, int out_size, void* d_ws, size_t ws_size,
                              hipStream_t stream)
{
    const float* s_j  = (const float*)d_in[0];
    const float* v_j  = (const float*)d_in[1];
    const float* r_ij = (const float*)d_in[2];
    const int*   nbrs = (const int*)d_in[3];
    const float* W1   = (const float*)d_in[4];
    const float* b1   = (const float*)d_in[5];
    const float* W2   = (const float*)d_in[6];
    const float* b2   = (const float*)d_in[7];
    const float* Wd   = (const float*)d_in[8];
    const float* bd   = (const float*)d_in[9];

    float* ds_out = (float*)d_out;
    float* dv_out = ds_out + (size_t)NNODES * FEAT;

    char* base = (char*)d_ws;
    short* pw            = (short*)base;                         // 155,648 B
    int*   hist          = (int*)(base + 160*1024);              // 100,000 B
    int*   cursor        = (int*)(base + 272*1024);              // 100,000 B
    int*   bsum          = (int*)(base + 376*1024);
    int*   boffs         = (int*)(base + 380*1024);
    int2*  recDS         = (int2*)(base + 512*1024);             // 3.2 MB
    float4* recR         = (float4*)(base + 4ull*1024*1024);     // 6.4 MB
    unsigned short* phiT = (unsigned short*)(base + 16ull*1024*1024); // 19.2 MB

    hipMemsetAsync(d_out, 0, (size_t)out_size * sizeof(float), stream);
    hipMemsetAsync(hist, 0, NNODES * sizeof(int), stream);

    prep_kernel<<<(PT_TOTAL + 255)/256, 256, 0, stream>>>(W1, W2, Wd, pw);
    nodephi_kernel<<<NPBLK, 256, 0, stream>>>(s_j, b1, b2, pw, phiT);
    hist_kernel<<<(NEDGES + 255)/256, 256, 0, stream>>>(nbrs, hist);
    scanA_kernel<<<NSCAN, 256, 0, stream>>>(hist, cursor, bsum);
    scanB_kernel<<<1, 128, 0, stream>>>(bsum, boffs);
    scanC_kernel<<<NSCAN, 256, 0, stream>>>(cursor, boffs);
    scatter_kernel<<<(NEDGES + 255)/256, 256, 0, stream>>>(nbrs, r_ij, cursor, recDS, recR);

    msg_kernel<<<NBLK, 256, 0, stream>>>(
        v_j, recDS, recR, bd, pw, phiT, ds_out, dv_out);
}